// Round 1
// baseline (518.749 us; speedup 1.0000x reference)
//
#include <hip/hip_runtime.h>
#include <math.h>

#define BB 8
#define CC 64
#define NN 32
#define CONV_TOTAL (BB*CC*NN*NN)   // 524288
#define KM_ELEMS (BB*9*CC*CC)      // 294912

// Kernel A: Kmat2[b][j][o*64+i] = 0.7*tanh(pre[b,o,i,j]) + (o==i && j==4)
// Also zeroes the 8 logdet accumulators in d_out.
__global__ __launch_bounds__(256) void build_km(const float* __restrict__ pre,
                                                float* __restrict__ km,
                                                float* __restrict__ logdet_out) {
    int idx = blockIdx.x * 256 + threadIdx.x;
    if (blockIdx.x == 0 && threadIdx.x < BB) logdet_out[threadIdx.x] = 0.f;
    if (idx >= KM_ELEMS) return;
    int b   = idx / (9 * 4096);
    int rem = idx - b * (9 * 4096);
    int j   = rem >> 12;       // tap 0..8
    int e   = rem & 4095;      // o*64+i
    int o = e >> 6, i = e & 63;
    float v = 0.7f * tanhf(pre[(b * 4096 + e) * 9 + j]);
    if (o == i && j == 4) v += 1.0f;
    km[idx] = v;
}

// Kernel B: direct circular conv. One block per (b,o); 256 threads; each
// thread owns 4 consecutive pixels in a row.
__global__ __launch_bounds__(256) void conv_kernel(const float* __restrict__ x,
                                                   const float* __restrict__ km,
                                                   const float* __restrict__ bias,
                                                   float* __restrict__ out) {
    int b = blockIdx.x >> 6, o = blockIdx.x & 63;
    __shared__ float Kms[9][64];
    __shared__ float xs[1024];
    int t = threadIdx.x;
    for (int s = t; s < 576; s += 256) {
        int j = s >> 6, i = s & 63;
        Kms[j][i] = km[(b * 9 + j) * 4096 + (o << 6) + i];
    }
    float bb = bias[(b << 6) + o];
    float acc0 = bb, acc1 = bb, acc2 = bb, acc3 = bb;
    int u = t >> 3, v0 = (t & 7) << 2;
    const float* xb = x + (size_t)(b << 6) * 1024;
    for (int i = 0; i < 64; ++i) {
        float4 xv4 = *(const float4*)(xb + i * 1024 + (t << 2));
        __syncthreads();                       // previous iter done reading xs
        *(float4*)&xs[t << 2] = xv4;
        __syncthreads();                       // xs (and Kms on iter 0) visible
        #pragma unroll
        for (int dy = 0; dy < 3; ++dy) {
            int row = (u + 1 - dy) & 31;
            const float* xr = &xs[row << 5];
            float xv[6];
            #pragma unroll
            for (int q = 0; q < 6; ++q) xv[q] = xr[(v0 - 1 + q) & 31];
            #pragma unroll
            for (int dx = 0; dx < 3; ++dx) {
                float w = Kms[dy * 3 + dx][i];
                acc0 += w * xv[2 - dx];
                acc1 += w * xv[3 - dx];
                acc2 += w * xv[4 - dx];
                acc3 += w * xv[5 - dx];
            }
        }
    }
    float4 r = make_float4(acc0, acc1, acc2, acc3);
    *(float4*)(out + ((size_t)blockIdx.x << 10) + (u << 5) + v0) = r;
}

// Kernel C: per-frequency 64x64 complex LU with partial pivoting.
// Conjugate-symmetry: only canonical (u,v) computed, weight 2 for pairs.
__global__ __launch_bounds__(256) void logdet_kernel(const float* __restrict__ km,
                                                     float* __restrict__ logdet_out) {
    int bid = blockIdx.x;
    int b = bid >> 10, f = bid & 1023;
    int u = f >> 5, v = f & 31;
    int u2 = (NN - u) & 31, v2 = (NN - v) & 31;
    if (u > u2 || (u == u2 && v > v2)) return;   // non-canonical
    float wgt = (u == u2 && v == v2) ? 1.0f : 2.0f;

    __shared__ float2 A[64][65];   // padded: breaks column-read bank conflict
    int t = threadIdx.x;

    // twiddles w[j] = exp(-2*pi*i*(u*(dy-1)+v*(dx-1))/32), exact via sincospif
    float wr[9], wi[9];
    #pragma unroll
    for (int j = 0; j < 9; ++j) {
        int dy = j / 3, dx = j % 3;
        float arg = -(float)(u * (dy - 1) + v * (dx - 1)) / 16.0f;  // angle/pi
        float s, c;
        sincospif(arg, &s, &c);
        wr[j] = c; wi[j] = s;
    }

    // Build A[o][i] = sum_j Kmat[b][j][o*64+i] * w[j]
    const float* Kb = km + (size_t)b * 36864;
    #pragma unroll
    for (int rep = 0; rep < 16; ++rep) {
        int e = t + (rep << 8);
        float re = 0.f, im = 0.f;
        #pragma unroll
        for (int j = 0; j < 9; ++j) {
            float kv = Kb[(j << 12) + e];
            re += kv * wr[j];
            im += kv * wi[j];
        }
        A[e >> 6][e & 63] = make_float2(re, im);
    }
    __syncthreads();

    int wave = t >> 6, lane = t & 63;
    float logsum = 0.f;   // meaningful on thread 0 only

    for (int k = 0; k < 64; ++k) {
        if (wave == 0) {
            // pivot argmax over rows >= k (butterfly, deterministic)
            float mag = -1.f; int idx = lane;
            if (lane >= k) { float2 a = A[lane][k]; mag = a.x * a.x + a.y * a.y; }
            #pragma unroll
            for (int s = 1; s < 64; s <<= 1) {
                float om = __shfl_xor(mag, s);
                int   oi = __shfl_xor(idx, s);
                if (om > mag) { mag = om; idx = oi; }
            }
            // swap rows k <-> idx (lane = column)
            if (idx != k) {
                float2 tmp = A[k][lane];
                A[k][lane] = A[idx][lane];
                A[idx][lane] = tmp;
            }
            if (lane == 0) logsum += 0.5f * logf(mag);
            // multipliers m = A[r][k] / pivot, stored in place
            float2 piv = A[k][k];            // same-wave DS ordering
            float inv = 1.0f / mag;
            if (lane > k) {
                float2 a = A[lane][k];
                float mr = (a.x * piv.x + a.y * piv.y) * inv;
                float mi = (a.y * piv.x - a.x * piv.y) * inv;
                A[lane][k] = make_float2(mr, mi);
            }
        }
        __syncthreads();
        // rank-1 update: 4 waves stride rows, lanes sweep columns
        for (int r = k + 1 + wave; r < 64; r += 4) {
            float2 m = A[r][k];              // wave-uniform broadcast read
            if (lane > k) {
                float2 p = A[k][lane];
                float2 a = A[r][lane];
                a.x -= m.x * p.x - m.y * p.y;
                a.y -= m.x * p.y + m.y * p.x;
                A[r][lane] = a;
            }
        }
        __syncthreads();
    }
    if (t == 0) atomicAdd(&logdet_out[b], wgt * logsum);
}

extern "C" void kernel_launch(void* const* d_in, const int* in_sizes, int n_in,
                              void* d_out, int out_size, void* d_ws, size_t ws_size,
                              hipStream_t stream) {
    const float* conv_in    = (const float*)d_in[0];
    const float* pre_kernel = (const float*)d_in[1];
    const float* bias       = (const float*)d_in[2];
    float* out = (float*)d_out;
    float* km  = (float*)d_ws;                 // 294912 floats = 1.18 MB
    float* logdet_out = out + CONV_TOTAL;

    build_km<<<KM_ELEMS / 256, 256, 0, stream>>>(pre_kernel, km, logdet_out);
    conv_kernel<<<BB * CC, 256, 0, stream>>>(conv_in, km, bias, out);
    logdet_kernel<<<BB * NN * NN, 256, 0, stream>>>(km, logdet_out);
}

// Round 2
// 404.163 us; speedup vs baseline: 1.2835x; 1.2835x over previous
//
#include <hip/hip_runtime.h>
#include <math.h>

#define BB 8
#define CC 64
#define NN 32
#define CONV_TOTAL (BB*CC*NN*NN)   // 524288
#define KM_ELEMS (BB*9*CC*CC)      // 294912
#define NCANON 514                 // canonical frequencies per batch

// Kernel A: km[b][j][o*64+i] = 0.7*tanh(pre[b,o,i,j]) + (o==i && j==4)
// Also zeroes the 8 logdet accumulators in d_out.
__global__ __launch_bounds__(256) void build_km(const float* __restrict__ pre,
                                                float* __restrict__ km,
                                                float* __restrict__ logdet_out) {
    int idx = blockIdx.x * 256 + threadIdx.x;
    if (blockIdx.x == 0 && threadIdx.x < BB) logdet_out[threadIdx.x] = 0.f;
    if (idx >= KM_ELEMS) return;
    int b   = idx / (9 * 4096);
    int rem = idx - b * (9 * 4096);
    int j   = rem >> 12;       // tap 0..8
    int e   = rem & 4095;      // o*64+i
    int o = e >> 6, i = e & 63;
    float v = 0.7f * tanhf(pre[(b * 4096 + e) * 9 + j]);
    if (o == i && j == 4) v += 1.0f;
    km[idx] = v;
}

// Kernel B: direct circular conv. One block per (b,o); 256 threads; each
// thread owns 4 consecutive pixels in a row.
__global__ __launch_bounds__(256) void conv_kernel(const float* __restrict__ x,
                                                   const float* __restrict__ km,
                                                   const float* __restrict__ bias,
                                                   float* __restrict__ out) {
    int b = blockIdx.x >> 6, o = blockIdx.x & 63;
    __shared__ float Kms[9][64];
    __shared__ float xs[1024];
    int t = threadIdx.x;
    for (int s = t; s < 576; s += 256) {
        int j = s >> 6, i = s & 63;
        Kms[j][i] = km[(b * 9 + j) * 4096 + (o << 6) + i];
    }
    float bb = bias[(b << 6) + o];
    float acc0 = bb, acc1 = bb, acc2 = bb, acc3 = bb;
    int u = t >> 3, v0 = (t & 7) << 2;
    const float* xb = x + (size_t)(b << 6) * 1024;
    for (int i = 0; i < 64; ++i) {
        float4 xv4 = *(const float4*)(xb + i * 1024 + (t << 2));
        __syncthreads();                       // previous iter done reading xs
        *(float4*)&xs[t << 2] = xv4;
        __syncthreads();                       // xs (and Kms on iter 0) visible
        #pragma unroll
        for (int dy = 0; dy < 3; ++dy) {
            int row = (u + 1 - dy) & 31;
            const float* xr = &xs[row << 5];
            float xv[6];
            #pragma unroll
            for (int q = 0; q < 6; ++q) xv[q] = xr[(v0 - 1 + q) & 31];
            #pragma unroll
            for (int dx = 0; dx < 3; ++dx) {
                float w = Kms[dy * 3 + dx][i];
                acc0 += w * xv[2 - dx];
                acc1 += w * xv[3 - dx];
                acc2 += w * xv[4 - dx];
                acc3 += w * xv[5 - dx];
            }
        }
    }
    float4 r = make_float4(acc0, acc1, acc2, acc3);
    *(float4*)(out + ((size_t)blockIdx.x << 10) + (u << 5) + v0) = r;
}

// Kernel C: per-frequency 64x64 complex UNPIVOTED LU.
// Only canonical (u,v) launched; conjugate pair contributes same log|det|
// (weight 2). One barrier per elimination step; all 4 waves update rows.
__global__ __launch_bounds__(256) void logdet_kernel(const float* __restrict__ km,
                                                     float* __restrict__ logdet_out) {
    int bid = blockIdx.x;
    int b = bid / NCANON, ci = bid - b * NCANON;
    // canonical index -> (u,v):
    //  ci 0..16    : u=0,  v=ci
    //  ci 17..496  : u=1+(ci-17)/32, v=(ci-17)%32
    //  ci 497..513 : u=16, v=ci-497
    int u, v;
    if (ci < 17)        { u = 0;                  v = ci; }
    else if (ci < 497)  { int r = ci - 17; u = 1 + (r >> 5); v = r & 31; }
    else                { u = 16;                 v = ci - 497; }
    float wgt = ((u == 0 || u == 16) && (v == 0 || v == 16)) ? 1.0f : 2.0f;

    __shared__ float2 As[64 * 64];   // 32 KB, row-major; all accesses row-wise
    int t = threadIdx.x;

    // twiddles w[j] = exp(-2*pi*i*(u*(dy-1)+v*(dx-1))/32), exact via sincospif
    float wr[9], wi[9];
    #pragma unroll
    for (int j = 0; j < 9; ++j) {
        int dy = j / 3, dx = j % 3;
        float arg = -(float)(u * (dy - 1) + v * (dx - 1)) / 16.0f;  // angle/pi
        float s, c;
        sincospif(arg, &s, &c);
        wr[j] = c; wi[j] = s;
    }

    // Build A[o*64+i] = sum_j km[b][j][o*64+i] * w[j]
    const float* Kb = km + (size_t)b * 36864;
    #pragma unroll
    for (int rep = 0; rep < 16; ++rep) {
        int e = t + (rep << 8);
        float re = 0.f, im = 0.f;
        #pragma unroll
        for (int j = 0; j < 9; ++j) {
            float kv = Kb[(j << 12) + e];
            re += kv * wr[j];
            im += kv * wi[j];
        }
        As[e] = make_float2(re, im);
    }

    int wave = t >> 6, lane = t & 63;

    for (int k = 0; k < 63; ++k) {
        __syncthreads();                      // step k-1 (or build) complete
        float2 piv = As[(k << 6) + k];        // broadcast read
        float inv = 1.0f / (piv.x * piv.x + piv.y * piv.y);
        int col = k + 1 + lane;
        bool act = col < 64;
        float2 pr = As[(k << 6) + (act ? col : k)];   // pivot-row element, cached
        for (int r = k + 1 + wave; r < 64; r += 4) {
            float2 ark = As[(r << 6) + k];    // wave-uniform broadcast
            float mr = (ark.x * piv.x + ark.y * piv.y) * inv;
            float mi = (ark.y * piv.x - ark.x * piv.y) * inv;
            if (act) {
                float2 a = As[(r << 6) + col];
                a.x -= mr * pr.x - mi * pr.y;
                a.y -= mr * pr.y + mi * pr.x;
                As[(r << 6) + col] = a;
            }
        }
    }
    __syncthreads();
    if (wave == 0) {
        float2 d = As[(lane << 6) + lane];
        float lg = 0.5f * logf(d.x * d.x + d.y * d.y);
        #pragma unroll
        for (int s = 1; s < 64; s <<= 1) lg += __shfl_xor(lg, s);
        if (lane == 0) atomicAdd(&logdet_out[b], wgt * lg);
    }
}

extern "C" void kernel_launch(void* const* d_in, const int* in_sizes, int n_in,
                              void* d_out, int out_size, void* d_ws, size_t ws_size,
                              hipStream_t stream) {
    const float* conv_in    = (const float*)d_in[0];
    const float* pre_kernel = (const float*)d_in[1];
    const float* bias       = (const float*)d_in[2];
    float* out = (float*)d_out;
    float* km  = (float*)d_ws;                 // 294912 floats = 1.18 MB
    float* logdet_out = out + CONV_TOTAL;

    build_km<<<KM_ELEMS / 256, 256, 0, stream>>>(pre_kernel, km, logdet_out);
    conv_kernel<<<BB * CC, 256, 0, stream>>>(conv_in, km, bias, out);
    logdet_kernel<<<BB * NCANON, 256, 0, stream>>>(km, logdet_out);
}